// Round 5
// baseline (291.408 us; speedup 1.0000x reference)
//
#include <hip/hip_runtime.h>

#define IMG 512
#define BATCH 64
#define ROWS_PER_STRIP 32
#define NSTEP 42   // 32 out rows + 10 halo rows

typedef float v2f __attribute__((ext_vector_type(2)));

__global__ __launch_bounds__(256, 4) void ssim_stream_kernel(
    const float* __restrict__ img1, const float* __restrict__ img2,
    const float* __restrict__ window, float* __restrict__ partials)
{
    __shared__ float wred[4];
    const int tid   = threadIdx.x;
    const int strip = blockIdx.x;      // 0..15
    const int b     = blockIdx.y;      // batch
    const int c0    = tid * 2;         // this thread's 2 output cols
    const int r_base = strip * ROWS_PER_STRIP;

    // 1-D gaussian = row sums of the 11x11 window (rows sum to g[k]); force SGPR
    float gw[11];
    #pragma unroll
    for (int k = 0; k < 11; ++k) {
        float s = 0.f;
        #pragma unroll
        for (int j = 0; j < 11; ++j) s += window[k*11 + j];
        gw[k] = __int_as_float(__builtin_amdgcn_readfirstlane(__float_as_int(s)));
    }

    const float* P1 = img1 + (size_t)b * (IMG*IMG);
    const float* P2 = img2 + (size_t)b * (IMG*IMG);

    const bool edge = (c0 < 6) || (c0 > IMG - 8);   // cols c0-6 .. c0+7 OOB risk

    // 11-slot ring of vertical accumulators: 5 channels, column-pair packed
    v2f acc[11][5];
    #pragma unroll
    for (int s = 0; s < 11; ++s)
        #pragma unroll
        for (int ch = 0; ch < 5; ++ch) acc[s][ch] = (v2f){0.f, 0.f};

    float thr_sum = 0.f;
    const float C1 = 1e-4f, C2 = 9e-4f;

    #pragma unroll 1
    for (int jj = 0; jj < 4; ++jj) {
      #pragma unroll
      for (int u = 0; u < 11; ++u) {
        const int t = jj*11 + u;            // stream step; t mod 11 == u (compile-time slots)
        if (t < NSTEP) {
          const int rr = r_base - 5 + t;    // raw image row

          float a[14], bb[14];
          if (rr >= 0 && rr < IMG) {
            const float* r1 = P1 + (size_t)rr * IMG;
            const float* r2 = P2 + (size_t)rr * IMG;
            if (!edge) {
              #pragma unroll
              for (int q = 0; q < 7; ++q) {   // words c0-6 .. c0+7, 8B-aligned
                float2 va = *(const float2*)(r1 + c0 - 6 + 2*q);
                float2 vb = *(const float2*)(r2 + c0 - 6 + 2*q);
                a[2*q]   = va.x; a[2*q+1]  = va.y;
                bb[2*q]  = vb.x; bb[2*q+1] = vb.y;
              }
            } else {
              #pragma unroll
              for (int e = 0; e < 14; ++e) {
                int gc = c0 - 6 + e;
                bool ok = (gc >= 0) && (gc < IMG);
                a[e]  = ok ? r1[gc] : 0.f;
                bb[e] = ok ? r2[gc] : 0.f;
              }
            }
          } else {
            #pragma unroll
            for (int e = 0; e < 14; ++e) { a[e] = 0.f; bb[e] = 0.f; }
          }

          // horizontal 5-channel conv for the 2 cols (scalar; shifted windows)
          // col0 window = a[1..11], col1 window = a[2..12]
          float h1c0=0.f,h2c0=0.f,h11c0=0.f,h22c0=0.f,h12c0=0.f;
          float h1c1=0.f,h2c1=0.f,h11c1=0.f,h22c1=0.f,h12c1=0.f;
          #pragma unroll
          for (int t2 = 1; t2 <= 12; ++t2) {
            float av = a[t2], bv = bb[t2];
            float pa = av*av, pb = bv*bv, pab = av*bv;
            if (t2 <= 11) {
              float w = gw[t2-1];
              h1c0 += w*av; h2c0 += w*bv; h11c0 += w*pa; h22c0 += w*pb; h12c0 += w*pab;
            }
            if (t2 >= 2) {
              float w = gw[t2-2];
              h1c1 += w*av; h2c1 += w*bv; h11c1 += w*pa; h22c1 += w*pb; h12c1 += w*pab;
            }
          }

          // pack column pairs once, then packed vertical FMA (v_pk_fma_f32)
          v2f hv[5];
          hv[0] = (v2f){h1c0,  h1c1};
          hv[1] = (v2f){h2c0,  h2c1};
          hv[2] = (v2f){h11c0, h11c1};
          hv[3] = (v2f){h22c0, h22c1};
          hv[4] = (v2f){h12c0, h12c1};

          // vertical accumulate: slot s takes tap k = 10 - ((s-u) mod 11)
          #pragma unroll
          for (int s = 0; s < 11; ++s) {
            const int k = 10 - (((s - u) % 11 + 11) % 11);
            const float w = gw[k];
            #pragma unroll
            for (int ch = 0; ch < 5; ++ch) acc[s][ch] += hv[ch] * w;
          }

          // slot u just received its last tap (out-row o = r_base - 10 + t)
          if (t >= 10) {
            v2f mu1 = acc[u][0], mu2 = acc[u][1];
            v2f mu1s = mu1*mu1, mu2s = mu2*mu2, mu12 = mu1*mu2;
            v2f s1  = acc[u][2] - mu1s;
            v2f s2  = acc[u][3] - mu2s;
            v2f s12 = acc[u][4] - mu12;
            v2f num = (2.f*mu12 + C1) * (2.f*s12 + C2);
            v2f den = (mu1s + mu2s + C1) * (s1 + s2 + C2);
            thr_sum += num.x/den.x + num.y/den.y;
          }
          #pragma unroll
          for (int ch = 0; ch < 5; ++ch) acc[u][ch] = (v2f){0.f, 0.f};
        }
      }
    }

    // block reduction
    for (int d = 32; d > 0; d >>= 1) thr_sum += __shfl_down(thr_sum, d, 64);
    int wid = tid >> 6, lane = tid & 63;
    if (lane == 0) wred[wid] = thr_sum;
    __syncthreads();
    if (tid == 0) {
        float s = wred[0] + wred[1] + wred[2] + wred[3];
        partials[blockIdx.y * 16 + blockIdx.x] = s;
    }
}

__global__ __launch_bounds__(256) void ssim_reduce_kernel(
    const float* __restrict__ partials, int n, float* __restrict__ out)
{
    __shared__ double wsumd[4];
    double s = 0.0;
    for (int i = threadIdx.x; i < n; i += 256) s += (double)partials[i];
    for (int d = 32; d > 0; d >>= 1) s += __shfl_down(s, d, 64);
    int wid = threadIdx.x >> 6, lane = threadIdx.x & 63;
    if (lane == 0) wsumd[wid] = s;
    __syncthreads();
    if (threadIdx.x == 0) {
        double t = wsumd[0] + wsumd[1] + wsumd[2] + wsumd[3];
        out[0] = (float)(t / ((double)BATCH * IMG * IMG));
    }
}

extern "C" void kernel_launch(void* const* d_in, const int* in_sizes, int n_in,
                              void* d_out, int out_size, void* d_ws, size_t ws_size,
                              hipStream_t stream) {
    const float* img1   = (const float*)d_in[0];
    const float* img2   = (const float*)d_in[1];
    const float* window = (const float*)d_in[2];
    float* out = (float*)d_out;
    float* partials = (float*)d_ws;

    dim3 grid(IMG / ROWS_PER_STRIP, BATCH);   // 16 x 64 = 1024 blocks -> 4 blocks/CU
    ssim_stream_kernel<<<grid, dim3(256), 0, stream>>>(img1, img2, window, partials);

    int npart = (IMG / ROWS_PER_STRIP) * BATCH;  // 1024
    ssim_reduce_kernel<<<1, 256, 0, stream>>>(partials, npart, out);
}

// Round 6
// 173.301 us; speedup vs baseline: 1.6815x; 1.6815x over previous
//
#include <hip/hip_runtime.h>

#define IMG 512
#define BATCH 64
#define ROWS_PER_STRIP 32
#define NSTEP 42   // 32 out rows + 10 halo rows

__global__ __launch_bounds__(256, 2) void ssim_stream_kernel(
    const float* __restrict__ img1, const float* __restrict__ img2,
    const float* __restrict__ window, float* __restrict__ partials)
{
    __shared__ float wred[4];
    const int tid   = threadIdx.x;
    const int strip = blockIdx.x;      // 0..15
    const int b     = blockIdx.y;      // batch
    const int c0    = tid * 2;         // this thread's 2 output cols
    const int r_base = strip * ROWS_PER_STRIP;

    // 1-D gaussian = row sums of the 11x11 window (rows sum to g[k]); force SGPR
    float gw[11];
    #pragma unroll
    for (int k = 0; k < 11; ++k) {
        float s = 0.f;
        #pragma unroll
        for (int j = 0; j < 11; ++j) s += window[k*11 + j];
        gw[k] = __int_as_float(__builtin_amdgcn_readfirstlane(__float_as_int(s)));
    }

    const float* P1 = img1 + (size_t)b * (IMG*IMG);
    const float* P2 = img2 + (size_t)b * (IMG*IMG);

    const bool edge = (c0 < 6) || (c0 > IMG - 8);   // cols c0-6 .. c0+7 OOB risk

    // 11-slot ring of vertical accumulators: 5 channels x 2 cols (scalar regs)
    float acc[11][5][2];
    #pragma unroll
    for (int s = 0; s < 11; ++s)
        #pragma unroll
        for (int ch = 0; ch < 5; ++ch) { acc[s][ch][0] = 0.f; acc[s][ch][1] = 0.f; }

    float thr_sum = 0.f;
    const float C1 = 1e-4f, C2 = 9e-4f;

    #pragma unroll 1
    for (int jj = 0; jj < 4; ++jj) {
      #pragma unroll
      for (int u = 0; u < 11; ++u) {
        const int t = jj*11 + u;            // stream step; t mod 11 == u (compile-time slots)
        if (t < NSTEP) {
          const int rr = r_base - 5 + t;    // raw image row

          float a[14], bb[14];
          if (rr >= 0 && rr < IMG) {
            const float* r1 = P1 + (size_t)rr * IMG;
            const float* r2 = P2 + (size_t)rr * IMG;
            if (!edge) {
              #pragma unroll
              for (int q = 0; q < 7; ++q) {   // words c0-6 .. c0+7, 8B-aligned
                float2 va = *(const float2*)(r1 + c0 - 6 + 2*q);
                float2 vb = *(const float2*)(r2 + c0 - 6 + 2*q);
                a[2*q]   = va.x; a[2*q+1]  = va.y;
                bb[2*q]  = vb.x; bb[2*q+1] = vb.y;
              }
            } else {
              #pragma unroll
              for (int e = 0; e < 14; ++e) {
                int gc = c0 - 6 + e;
                bool ok = (gc >= 0) && (gc < IMG);
                a[e]  = ok ? r1[gc] : 0.f;
                bb[e] = ok ? r2[gc] : 0.f;
              }
            }
          } else {
            #pragma unroll
            for (int e = 0; e < 14; ++e) { a[e] = 0.f; bb[e] = 0.f; }
          }

          // horizontal 5-channel conv for the 2 cols.
          // col0 window = a[1..11], col1 window = a[2..12]
          float h1c0=0.f,h2c0=0.f,h11c0=0.f,h22c0=0.f,h12c0=0.f;
          float h1c1=0.f,h2c1=0.f,h11c1=0.f,h22c1=0.f,h12c1=0.f;
          #pragma unroll
          for (int t2 = 1; t2 <= 12; ++t2) {
            float av = a[t2], bv = bb[t2];
            float pa = av*av, pb = bv*bv, pab = av*bv;
            if (t2 <= 11) {
              float w = gw[t2-1];
              h1c0 += w*av; h2c0 += w*bv; h11c0 += w*pa; h22c0 += w*pb; h12c0 += w*pab;
            }
            if (t2 >= 2) {
              float w = gw[t2-2];
              h1c1 += w*av; h2c1 += w*bv; h11c1 += w*pa; h22c1 += w*pb; h12c1 += w*pab;
            }
          }

          // vertical accumulate: slot s takes tap k = 10 - ((s-u) mod 11)
          #pragma unroll
          for (int s = 0; s < 11; ++s) {
            const int k = 10 - (((s - u) % 11 + 11) % 11);
            const float w = gw[k];
            acc[s][0][0] += w*h1c0;  acc[s][0][1] += w*h1c1;
            acc[s][1][0] += w*h2c0;  acc[s][1][1] += w*h2c1;
            acc[s][2][0] += w*h11c0; acc[s][2][1] += w*h11c1;
            acc[s][3][0] += w*h22c0; acc[s][3][1] += w*h22c1;
            acc[s][4][0] += w*h12c0; acc[s][4][1] += w*h12c1;
          }

          // slot u just received its last tap (out-row o = r_base - 10 + t)
          if (t >= 10) {
            #pragma unroll
            for (int cc = 0; cc < 2; ++cc) {
              float mu1 = acc[u][0][cc], mu2 = acc[u][1][cc];
              float mu1s = mu1*mu1, mu2s = mu2*mu2, mu12 = mu1*mu2;
              float s1  = acc[u][2][cc] - mu1s;
              float s2  = acc[u][3][cc] - mu2s;
              float s12 = acc[u][4][cc] - mu12;
              float num = (2.f*mu12 + C1) * (2.f*s12 + C2);
              float den = (mu1s + mu2s + C1) * (s1 + s2 + C2);
              thr_sum += num / den;
            }
          }
          #pragma unroll
          for (int ch = 0; ch < 5; ++ch) { acc[u][ch][0] = 0.f; acc[u][ch][1] = 0.f; }
        }
      }
    }

    // block reduction
    for (int d = 32; d > 0; d >>= 1) thr_sum += __shfl_down(thr_sum, d, 64);
    int wid = tid >> 6, lane = tid & 63;
    if (lane == 0) wred[wid] = thr_sum;
    __syncthreads();
    if (tid == 0) {
        float s = wred[0] + wred[1] + wred[2] + wred[3];
        partials[blockIdx.y * 16 + blockIdx.x] = s;
    }
}

__global__ __launch_bounds__(256) void ssim_reduce_kernel(
    const float* __restrict__ partials, int n, float* __restrict__ out)
{
    __shared__ double wsumd[4];
    double s = 0.0;
    for (int i = threadIdx.x; i < n; i += 256) s += (double)partials[i];
    for (int d = 32; d > 0; d >>= 1) s += __shfl_down(s, d, 64);
    int wid = threadIdx.x >> 6, lane = threadIdx.x & 63;
    if (lane == 0) wsumd[wid] = s;
    __syncthreads();
    if (threadIdx.x == 0) {
        double t = wsumd[0] + wsumd[1] + wsumd[2] + wsumd[3];
        out[0] = (float)(t / ((double)BATCH * IMG * IMG));
    }
}

extern "C" void kernel_launch(void* const* d_in, const int* in_sizes, int n_in,
                              void* d_out, int out_size, void* d_ws, size_t ws_size,
                              hipStream_t stream) {
    const float* img1   = (const float*)d_in[0];
    const float* img2   = (const float*)d_in[1];
    const float* window = (const float*)d_in[2];
    float* out = (float*)d_out;
    float* partials = (float*)d_ws;

    dim3 grid(IMG / ROWS_PER_STRIP, BATCH);   // 16 x 64 = 1024 blocks -> 4 blocks/CU
    ssim_stream_kernel<<<grid, dim3(256), 0, stream>>>(img1, img2, window, partials);

    int npart = (IMG / ROWS_PER_STRIP) * BATCH;  // 1024
    ssim_reduce_kernel<<<1, 256, 0, stream>>>(partials, npart, out);
}

// Round 7
// 101.871 us; speedup vs baseline: 2.8606x; 1.7012x over previous
//
#include <hip/hip_runtime.h>

#define IMG 512
#define BATCH 64
#define RPS 32          // output rows per strip
#define NSTEP 42        // RPS + 10 halo rows
#define LDSW 528        // words per staged row; word = col + 8 (cols -8..519, pads zeroed)

__global__ __launch_bounds__(256, 2) void ssim_ring_kernel(
    const float* __restrict__ img1, const float* __restrict__ img2,
    const float* __restrict__ window, float* __restrict__ partials)
{
    __shared__ float srow[2][2][LDSW];   // [buf][img][word]  8448 B
    __shared__ float wred[4];

    const int tid   = threadIdx.x;
    const int strip = blockIdx.x;        // 0..15
    const int b     = blockIdx.y;        // batch
    const int c0    = tid * 2;           // this thread's 2 output cols
    const int r_base = strip * RPS;

    // 1-D gaussian = row sums of the 11x11 window; force to SGPR
    float gw[11];
    #pragma unroll
    for (int k = 0; k < 11; ++k) {
        float s = 0.f;
        #pragma unroll
        for (int j = 0; j < 11; ++j) s += window[k*11 + j];
        gw[k] = __int_as_float(__builtin_amdgcn_readfirstlane(__float_as_int(s)));
    }

    const float* P1 = img1 + (size_t)b * (IMG*IMG);
    const float* P2 = img2 + (size_t)b * (IMG*IMG);

    // staging assignment: 132 float4-chunks per image row (words 4j..4j+3, col 4j-8)
    const int   jA   = (tid < 132) ? tid : tid - 132;
    const float* PA  = (tid < 132) ? P1 : P2;
    const int   imA  = (tid < 132) ? 0 : 1;
    const int   colA = 4*jA - 8;
    const bool  okA  = (colA >= 0) && (colA <= IMG-4);
    const bool  hasB = (tid < 8);              // img2 chunks 124..131
    const int   jB   = 124 + tid;
    const int   colB = 4*jB - 8;
    const bool  okB  = hasB && (colB >= 0) && (colB <= IMG-4);

    // prefill: stage raw row (r_base-5) into buf 0
    {
        int rr = r_base - 5;
        bool rowok = (rr >= 0) && (rr < IMG);
        float4 vA = {0,0,0,0}, vB = {0,0,0,0};
        if (rowok && okA) vA = *(const float4*)(PA + (size_t)rr*IMG + colA);
        if (rowok && okB) vB = *(const float4*)(P2 + (size_t)rr*IMG + colB);
        *(float4*)&srow[0][imA][4*jA] = vA;
        if (hasB) *(float4*)&srow[0][1][4*jB] = vB;
    }
    __syncthreads();

    // 11-slot ring of vertical accumulators: 5 channels x 2 cols
    float acc[11][5][2];
    #pragma unroll
    for (int s = 0; s < 11; ++s)
        #pragma unroll
        for (int ch = 0; ch < 5; ++ch) { acc[s][ch][0] = 0.f; acc[s][ch][1] = 0.f; }

    float thr_sum = 0.f;
    const float C1 = 1e-4f, C2 = 9e-4f;

    #pragma unroll 1
    for (int jj = 0; jj < 4; ++jj) {
      #pragma unroll
      for (int u = 0; u < 11; ++u) {
        const int t = jj*11 + u;               // t mod 11 == u (compile-time ring slots)
        if (t < NSTEP) {
          // (1) issue global loads for next row early (hide under compute)
          float4 vA = {0,0,0,0}, vB = {0,0,0,0};
          const bool do_stage = (t+1 < NSTEP);
          if (do_stage) {
            int rr = r_base - 5 + t + 1;
            bool rowok = (rr >= 0) && (rr < IMG);
            if (rowok && okA) vA = *(const float4*)(PA + (size_t)rr*IMG + colA);
            if (rowok && okB) vB = *(const float4*)(P2 + (size_t)rr*IMG + colB);
          }

          // (2) read this step's row from LDS: 7 x b64 per image, conflict-free
          const float* L1 = &srow[t & 1][0][0];
          const float* L2 = &srow[t & 1][1][0];
          float a[14], bb[14];
          #pragma unroll
          for (int q = 0; q < 7; ++q) {        // words 2(tid+1+q), 2(tid+1+q)+1
            float2 va = *(const float2*)&L1[2*(tid + 1 + q)];
            float2 vb = *(const float2*)&L2[2*(tid + 1 + q)];
            a[2*q]   = va.x; a[2*q+1]  = va.y; // a[e] = col c0-6+e
            bb[2*q]  = vb.x; bb[2*q+1] = vb.y;
          }

          // horizontal 5-channel conv for the 2 cols
          // col0 window = a[1..11], col1 window = a[2..12]
          float h1c0=0.f,h2c0=0.f,h11c0=0.f,h22c0=0.f,h12c0=0.f;
          float h1c1=0.f,h2c1=0.f,h11c1=0.f,h22c1=0.f,h12c1=0.f;
          #pragma unroll
          for (int t2 = 1; t2 <= 12; ++t2) {
            float av = a[t2], bv = bb[t2];
            float pa = av*av, pb = bv*bv, pab = av*bv;
            if (t2 <= 11) {
              float w = gw[t2-1];
              h1c0 += w*av; h2c0 += w*bv; h11c0 += w*pa; h22c0 += w*pb; h12c0 += w*pab;
            }
            if (t2 >= 2) {
              float w = gw[t2-2];
              h1c1 += w*av; h2c1 += w*bv; h11c1 += w*pa; h22c1 += w*pb; h12c1 += w*pab;
            }
          }

          // vertical ring accumulate: slot s takes tap k = 10 - ((s-u) mod 11)
          #pragma unroll
          for (int s = 0; s < 11; ++s) {
            const int k = 10 - (((s - u) % 11 + 11) % 11);
            const float w = gw[k];
            acc[s][0][0] += w*h1c0;  acc[s][0][1] += w*h1c1;
            acc[s][1][0] += w*h2c0;  acc[s][1][1] += w*h2c1;
            acc[s][2][0] += w*h11c0; acc[s][2][1] += w*h11c1;
            acc[s][3][0] += w*h22c0; acc[s][3][1] += w*h22c1;
            acc[s][4][0] += w*h12c0; acc[s][4][1] += w*h12c1;
          }

          // slot u completed its 11 taps (out-row r_base - 10 + t)
          if (t >= 10) {
            #pragma unroll
            for (int cc = 0; cc < 2; ++cc) {
              float mu1 = acc[u][0][cc], mu2 = acc[u][1][cc];
              float mu1s = mu1*mu1, mu2s = mu2*mu2, mu12 = mu1*mu2;
              float s1  = acc[u][2][cc] - mu1s;
              float s2  = acc[u][3][cc] - mu2s;
              float s12 = acc[u][4][cc] - mu12;
              float num = (2.f*mu12 + C1) * (2.f*s12 + C2);
              float den = (mu1s + mu2s + C1) * (s1 + s2 + C2);
              thr_sum += num / den;
            }
          }
          #pragma unroll
          for (int ch = 0; ch < 5; ++ch) { acc[u][ch][0] = 0.f; acc[u][ch][1] = 0.f; }

          // (3) write staged row to the other buffer, then step barrier
          if (do_stage) {
            *(float4*)&srow[(t+1) & 1][imA][4*jA] = vA;
            if (hasB) *(float4*)&srow[(t+1) & 1][1][4*jB] = vB;
          }
          __syncthreads();
        }
      }
    }

    // block reduction
    for (int d = 32; d > 0; d >>= 1) thr_sum += __shfl_down(thr_sum, d, 64);
    int wid = tid >> 6, lane = tid & 63;
    if (lane == 0) wred[wid] = thr_sum;
    __syncthreads();
    if (tid == 0) {
        float s = wred[0] + wred[1] + wred[2] + wred[3];
        partials[blockIdx.y * 16 + blockIdx.x] = s;
    }
}

__global__ __launch_bounds__(256) void ssim_reduce_kernel(
    const float* __restrict__ partials, int n, float* __restrict__ out)
{
    __shared__ double wsumd[4];
    double s = 0.0;
    for (int i = threadIdx.x; i < n; i += 256) s += (double)partials[i];
    for (int d = 32; d > 0; d >>= 1) s += __shfl_down(s, d, 64);
    int wid = threadIdx.x >> 6, lane = threadIdx.x & 63;
    if (lane == 0) wsumd[wid] = s;
    __syncthreads();
    if (threadIdx.x == 0) {
        double t = wsumd[0] + wsumd[1] + wsumd[2] + wsumd[3];
        out[0] = (float)(t / ((double)BATCH * IMG * IMG));
    }
}

extern "C" void kernel_launch(void* const* d_in, const int* in_sizes, int n_in,
                              void* d_out, int out_size, void* d_ws, size_t ws_size,
                              hipStream_t stream) {
    const float* img1   = (const float*)d_in[0];
    const float* img2   = (const float*)d_in[1];
    const float* window = (const float*)d_in[2];
    float* out = (float*)d_out;
    float* partials = (float*)d_ws;

    dim3 grid(IMG / RPS, BATCH);   // 16 x 64 = 1024 blocks
    ssim_ring_kernel<<<grid, dim3(256), 0, stream>>>(img1, img2, window, partials);

    int npart = (IMG / RPS) * BATCH;  // 1024
    ssim_reduce_kernel<<<1, 256, 0, stream>>>(partials, npart, out);
}

// Round 8
// 80.919 us; speedup vs baseline: 3.6012x; 1.2589x over previous
//
#include <hip/hip_runtime.h>

#define IMG 512
#define BATCH 64
#define RPS 32          // output rows per strip
#define NSTEP 42        // RPS + 10 halo rows
#define LDSW 528        // words per staged row; word = col + 8 (cols -8..519, pads zeroed)

typedef float v2f __attribute__((ext_vector_type(2)));

__global__ __launch_bounds__(256, 2) void ssim_ring_kernel(
    const float* __restrict__ img1, const float* __restrict__ img2,
    const float* __restrict__ window, float* __restrict__ partials)
{
    __shared__ float srow[2][2][LDSW];   // [buf][img][word]  8448 B
    __shared__ float wred[4];

    const int tid   = threadIdx.x;
    const int strip = blockIdx.x;        // 0..15
    const int b     = blockIdx.y;        // batch
    const int r_base = strip * RPS;

    // 1-D gaussian = row sums of the 11x11 window; force to SGPR
    float gw[11];
    #pragma unroll
    for (int k = 0; k < 11; ++k) {
        float s = 0.f;
        #pragma unroll
        for (int j = 0; j < 11; ++j) s += window[k*11 + j];
        gw[k] = __int_as_float(__builtin_amdgcn_readfirstlane(__float_as_int(s)));
    }

    const float* P1 = img1 + (size_t)b * (IMG*IMG);
    const float* P2 = img2 + (size_t)b * (IMG*IMG);

    // staging assignment: 132 float4-chunks per image row (words 4j..4j+3, col 4j-8)
    const int   jA   = (tid < 132) ? tid : tid - 132;
    const float* PA  = (tid < 132) ? P1 : P2;
    const int   imA  = (tid < 132) ? 0 : 1;
    const int   colA = 4*jA - 8;
    const bool  okA  = (colA >= 0) && (colA <= IMG-4);
    const bool  hasB = (tid < 8);              // img2 chunks 124..131
    const int   jB   = 124 + tid;
    const int   colB = 4*jB - 8;
    const bool  okB  = hasB && (colB >= 0) && (colB <= IMG-4);

    // prefill: stage raw row (r_base-5) into buf 0
    {
        int rr = r_base - 5;
        bool rowok = (rr >= 0) && (rr < IMG);
        float4 vA = {0,0,0,0}, vB = {0,0,0,0};
        if (rowok && okA) vA = *(const float4*)(PA + (size_t)rr*IMG + colA);
        if (rowok && okB) vB = *(const float4*)(P2 + (size_t)rr*IMG + colB);
        *(float4*)&srow[0][imA][4*jA] = vA;
        if (hasB) *(float4*)&srow[0][1][4*jB] = vB;
    }
    __syncthreads();

    // 11-slot ring of vertical accumulators: 5 channels, col-pair packed
    v2f acc[11][5];
    #pragma unroll
    for (int s = 0; s < 11; ++s)
        #pragma unroll
        for (int ch = 0; ch < 5; ++ch) acc[s][ch] = (v2f){0.f, 0.f};

    v2f rsum = (v2f){0.f, 0.f};
    const float C1 = 1e-4f, C2 = 9e-4f;

    #pragma unroll 1
    for (int jj = 0; jj < 4; ++jj) {
      #pragma unroll
      for (int u = 0; u < 11; ++u) {
        const int t = jj*11 + u;               // t mod 11 == u (compile-time ring slots)
        if (t < NSTEP) {
          // (1) issue global loads for next row early (hide under compute)
          float4 vA = {0,0,0,0}, vB = {0,0,0,0};
          const bool do_stage = (t+1 < NSTEP);
          if (do_stage) {
            int rr = r_base - 5 + t + 1;
            bool rowok = (rr >= 0) && (rr < IMG);
            if (rowok && okA) vA = *(const float4*)(PA + (size_t)rr*IMG + colA);
            if (rowok && okB) vB = *(const float4*)(P2 + (size_t)rr*IMG + colB);
          }

          // (2) read this step's row from LDS: 7 x b64 per image
          const float* Lp1 = &srow[t & 1][0][0];
          const float* Lp2 = &srow[t & 1][1][0];
          v2f L1[7], L2[7];                    // L[q] = (a[2q], a[2q+1]), a[e] = col c0-6+e
          #pragma unroll
          for (int q = 0; q < 7; ++q) {
            L1[q] = *(const v2f*)&Lp1[2*(tid + 1 + q)];
            L2[q] = *(const v2f*)&Lp2[2*(tid + 1 + q)];
          }

          // (3) packed horizontal conv: pA[k]=(a[k+1],a[k+2]) feeds both cols at once
          v2f h1 = (v2f){0,0}, h2 = (v2f){0,0};
          v2f h11 = (v2f){0,0}, h22 = (v2f){0,0}, h12 = (v2f){0,0};
          #pragma unroll
          for (int k = 0; k < 11; ++k) {
            v2f pa, pb;
            if (k & 1) {                       // k odd: natural pair L[(k+1)/2]
              pa = L1[(k+1) >> 1]; pb = L2[(k+1) >> 1];
            } else {                           // k even: straddling pair
              pa = __builtin_shufflevector(L1[k>>1], L1[(k>>1)+1], 1, 2);
              pb = __builtin_shufflevector(L2[k>>1], L2[(k>>1)+1], 1, 2);
            }
            float w = gw[k];
            h1  += w * pa;
            h2  += w * pb;
            h11 += w * (pa * pa);
            h22 += w * (pb * pb);
            h12 += w * (pa * pb);
          }

          // (4) packed vertical ring accumulate: slot s takes tap k = 10 - ((s-u) mod 11)
          #pragma unroll
          for (int s = 0; s < 11; ++s) {
            const int k = 10 - (((s - u) % 11 + 11) % 11);
            const float w = gw[k];
            acc[s][0] += w * h1;
            acc[s][1] += w * h2;
            acc[s][2] += w * h11;
            acc[s][3] += w * h22;
            acc[s][4] += w * h12;
          }

          // (5) slot u completed its 11 taps (out-row r_base - 10 + t)
          if (t >= 10) {
            v2f mu1 = acc[u][0], mu2 = acc[u][1];
            v2f mu1s = mu1*mu1, mu2s = mu2*mu2, mu12 = mu1*mu2;
            v2f s1  = acc[u][2] - mu1s;
            v2f s2  = acc[u][3] - mu2s;
            v2f s12 = acc[u][4] - mu12;
            v2f num = (2.f*mu12 + C1) * (2.f*s12 + C2);
            v2f den = (mu1s + mu2s + C1) * (s1 + s2 + C2);
            v2f r;
            r.x = num.x * __builtin_amdgcn_rcpf(den.x);
            r.y = num.y * __builtin_amdgcn_rcpf(den.y);
            rsum += r;
          }
          #pragma unroll
          for (int ch = 0; ch < 5; ++ch) acc[u][ch] = (v2f){0.f, 0.f};

          // (6) write staged row to the other buffer, then step barrier
          if (do_stage) {
            *(float4*)&srow[(t+1) & 1][imA][4*jA] = vA;
            if (hasB) *(float4*)&srow[(t+1) & 1][1][4*jB] = vB;
          }
          __syncthreads();
        }
      }
    }

    float thr_sum = rsum.x + rsum.y;

    // block reduction
    for (int d = 32; d > 0; d >>= 1) thr_sum += __shfl_down(thr_sum, d, 64);
    int wid = tid >> 6, lane = tid & 63;
    if (lane == 0) wred[wid] = thr_sum;
    __syncthreads();
    if (tid == 0) {
        float s = wred[0] + wred[1] + wred[2] + wred[3];
        partials[blockIdx.y * 16 + blockIdx.x] = s;
    }
}

__global__ __launch_bounds__(256) void ssim_reduce_kernel(
    const float* __restrict__ partials, int n, float* __restrict__ out)
{
    __shared__ double wsumd[4];
    double s = 0.0;
    for (int i = threadIdx.x; i < n; i += 256) s += (double)partials[i];
    for (int d = 32; d > 0; d >>= 1) s += __shfl_down(s, d, 64);
    int wid = threadIdx.x >> 6, lane = threadIdx.x & 63;
    if (lane == 0) wsumd[wid] = s;
    __syncthreads();
    if (threadIdx.x == 0) {
        double t = wsumd[0] + wsumd[1] + wsumd[2] + wsumd[3];
        out[0] = (float)(t / ((double)BATCH * IMG * IMG));
    }
}

extern "C" void kernel_launch(void* const* d_in, const int* in_sizes, int n_in,
                              void* d_out, int out_size, void* d_ws, size_t ws_size,
                              hipStream_t stream) {
    const float* img1   = (const float*)d_in[0];
    const float* img2   = (const float*)d_in[1];
    const float* window = (const float*)d_in[2];
    float* out = (float*)d_out;
    float* partials = (float*)d_ws;

    dim3 grid(IMG / RPS, BATCH);   // 16 x 64 = 1024 blocks
    ssim_ring_kernel<<<grid, dim3(256), 0, stream>>>(img1, img2, window, partials);

    int npart = (IMG / RPS) * BATCH;  // 1024
    ssim_reduce_kernel<<<1, 256, 0, stream>>>(partials, npart, out);
}